// Round 8
// baseline (107.867 us; speedup 1.0000x reference)
//
#include <hip/hip_runtime.h>
#include <hip/hip_bf16.h>
#include <stdint.h>

using bf16x8 = __attribute__((ext_vector_type(8))) short;
using f32x4  = __attribute__((ext_vector_type(4))) float;

#define N_NODES  50000
#define K1       768
#define D1       512
#define NPAIR    16384
#define NOUT     97
#define NOUT_PAD 112
#define BM       64
#define MT       782             // ceil(50000/64)
#define KSTEPS   24              // 768/32

__device__ __forceinline__ uint16_t f2bf(float f) {
    uint32_t u = __builtin_bit_cast(uint32_t, f);
    return (uint16_t)((u + 0x7fffu + ((u >> 16) & 1u)) >> 16);  // RNE
}

// async global->LDS DMA, 16B/lane; LDS dest = wave-uniform base + lane*16
__device__ __forceinline__ void gll16(const void* g, void* l) {
    __builtin_amdgcn_global_load_lds(
        (const __attribute__((address_space(1))) void*)g,
        (__attribute__((address_space(3))) void*)l, 16, 0, 0);
}

// ---- convert: W1[768][512] -> W1t bf16 [512][768]; Wp[1024][97] -> Wpt bf16 [112][1024] ----
__global__ void k_convert(const float* __restrict__ W1, const float* __restrict__ Wp,
                          uint16_t* __restrict__ W1t, uint16_t* __restrict__ Wpt) {
    int idx = blockIdx.x * 256 + threadIdx.x;
    const int n1 = D1 * K1;
    if (idx < n1) {
        int c = idx / K1, k = idx - c * K1;
        W1t[idx] = f2bf(W1[k * D1 + c]);
    } else {
        int j = idx - n1;
        if (j < NOUT_PAD * 1024) {
            int c = j >> 10, k = j & 1023;
            Wpt[j] = (c < NOUT) ? f2bf(Wp[k * NOUT + c]) : (uint16_t)0;
        }
    }
}

// ---- GEMM1: H[50000][512] = relu(A @ W1 + b1) ----
// 64x512 tile (A fetched exactly once), 8 waves (1x8), BK=32.
// A: reg-staged fp32->bf16 (RNE bit-ops), loads issued 2 iterations ahead.
// B: gll16 DMA, double-buffered, counted vmcnt (never drained in-loop).
// INVARIANT (m201): every wave retires its ds_reads via an explicit
// lgkmcnt(0) BEFORE crossing the reads-done barrier — raw s_barrier gives
// no such guarantee and hipcc may sink MFMAs (with their implicit waits)
// past it (rule #18), letting next-tile writes race pending reads.
__global__ __launch_bounds__(512, 4) void k_gemm1(const float* __restrict__ A,
        const uint16_t* __restrict__ W1t, const float* __restrict__ bias1,
        uint16_t* __restrict__ H) {
    __shared__ uint16_t lds_a[2][BM * 32];    //  8 KB total
    __shared__ uint16_t lds_b[2][D1 * 32];    // 64 KB total

    const int bid = blockIdx.x;
    const int m0 = bid * BM;
    const int t = threadIdx.x, lane = t & 63, wv = t >> 6;
    const int cl = lane & 15, kh = lane >> 4;

    // --- A staging (reg path): thread t covers row t>>3, floats [(t&7)*4, +4)
    int arow_g = m0 + (t >> 3); if (arow_g >= N_NODES) arow_g = N_NODES - 1;
    const float4* aSrc = (const float4*)(A + (size_t)arow_g * K1) + (t & 7);  // +8 per K-step
    // ds_write dest: row=t>>3, logical 8-elem chunk c=(t&7)>>1, half=t&1,
    // phys chunk p = c ^ ((row>>1)&3) = ((t&7)>>1) ^ ((t>>4)&3)
    uint16_t* aWr = &lds_a[0][(t >> 3) * 32 + ((((t & 7) >> 1) ^ ((t >> 4) & 3)) * 8) + (t & 1) * 4];

    // --- B staging (DMA): instr i covers rows i*128 + (t>>2), phys chunk t&3 (linear dest);
    //     source logical chunk c = (t&3) ^ ((t>>3)&3)  (pre-swizzle, rule #21)
    const uint16_t* bBase = W1t + (size_t)(t >> 2) * K1 + (((t & 3) ^ ((t >> 3) & 3)) * 8);

    // --- fragment read chunk offset: phys = kh ^ ((row>>1)&3), (row>>1)&3 == (cl>>1)&3
    const int fo = (kh ^ ((cl >> 1) & 3)) * 8;

    f32x4 acc[4][4];
    const f32x4 z = {0.f, 0.f, 0.f, 0.f};
    #pragma unroll
    for (int m = 0; m < 4; ++m)
        #pragma unroll
        for (int n = 0; n < 4; ++n) acc[m][n] = z;

#define STAGE_B(K, BUF) do {                                                   \
    _Pragma("unroll")                                                          \
    for (int i_ = 0; i_ < 4; ++i_)                                             \
        gll16(bBase + (size_t)i_ * (128 * K1) + (K) * 32,                      \
              &lds_b[BUF][i_ * 4096 + wv * 512]);                              \
    } while (0)

#define WRITE_A(BUF, R) do {                                                   \
    uint32_t lo_ = (uint32_t)f2bf((R).x) | ((uint32_t)f2bf((R).y) << 16);      \
    uint32_t hi_ = (uint32_t)f2bf((R).z) | ((uint32_t)f2bf((R).w) << 16);      \
    uint2 v_ = {lo_, hi_};                                                     \
    *(uint2*)(aWr + (BUF) * (BM * 32)) = v_;                                   \
    } while (0)

#define COMPUTE(BUF) do {                                                      \
    const uint16_t* la_ = &lds_a[BUF][0];                                      \
    const uint16_t* lb_ = &lds_b[BUF][0];                                      \
    bf16x8 af_[4], bq_[4];                                                     \
    _Pragma("unroll")                                                          \
    for (int mf = 0; mf < 4; ++mf)                                             \
        af_[mf] = *(const bf16x8*)&la_[(mf * 16 + cl) * 32 + fo];              \
    _Pragma("unroll")                                                          \
    for (int nf = 0; nf < 4; ++nf)                                             \
        bq_[nf] = *(const bf16x8*)&lb_[(wv * 64 + nf * 16 + cl) * 32 + fo];    \
    _Pragma("unroll")                                                          \
    for (int mf = 0; mf < 4; ++mf)                                             \
        _Pragma("unroll")                                                      \
        for (int nf = 0; nf < 4; ++nf)                                         \
            acc[mf][nf] = __builtin_amdgcn_mfma_f32_16x16x32_bf16(             \
                              af_[mf], bq_[nf], acc[mf][nf], 0, 0, 0);         \
    } while (0)

// reads-done fence: pin the compute cluster, retire THIS wave's ds_reads,
// then cross the barrier. Only after this may anyone write the buffer.
#define READS_DONE_BARRIER() do {                                              \
    __builtin_amdgcn_sched_barrier(0);                                         \
    asm volatile("s_waitcnt lgkmcnt(0)" ::: "memory");                         \
    __builtin_amdgcn_s_barrier();                                              \
    } while (0)

    // ---- prologue: tiles 0,1 staged; A depth-2 pipeline primed
    float4 rA0 = aSrc[0];          // A(0)
    float4 rA1 = aSrc[8];          // A(1)
    STAGE_B(0, 0);
    STAGE_B(1, 1);
    WRITE_A(0, rA0);               // A(0) -> buf0 (compiler waits its load)
    rA0 = aSrc[16];                // A(2)
    WRITE_A(1, rA1);               // A(1) -> buf1
    rA1 = aSrc[24];                // A(3)
    asm volatile("s_waitcnt vmcnt(6)" ::: "memory");   // B(0) landed; B(1)+A(2)+A(3) in flight
    asm volatile("s_waitcnt lgkmcnt(0)" ::: "memory");
    __builtin_amdgcn_s_barrier();

    // ---- steady state: ktc = 0..19
    for (int ktc = 0; ktc < 20; ++ktc) {
        COMPUTE(ktc & 1);                              // tile ktc
        READS_DONE_BARRIER();                          // buf (ktc&1) free
        STAGE_B(ktc + 2, ktc & 1);                     // B(ktc+2) -> freed buf
        WRITE_A(ktc & 1, rA0);                         // A(ktc+2) -> freed buf
        rA0 = rA1;
        rA1 = aSrc[(ktc + 4) * 8];                     // A(ktc+4): 2-iter depth
        asm volatile("s_waitcnt vmcnt(6)" ::: "memory");  // B(ktc+1) landed
        asm volatile("s_waitcnt lgkmcnt(0)" ::: "memory");
        __builtin_amdgcn_s_barrier();                  // tile ktc+1 ready
    }
    // ---- tail: tiles 20..23
    COMPUTE(0);                                        // tile 20
    READS_DONE_BARRIER();
    STAGE_B(22, 0);
    WRITE_A(0, rA0);                                   // A(22)
    rA0 = rA1;                                         // A(23)
    asm volatile("s_waitcnt vmcnt(5)" ::: "memory");   // B(21) landed
    asm volatile("s_waitcnt lgkmcnt(0)" ::: "memory");
    __builtin_amdgcn_s_barrier();

    COMPUTE(1);                                        // tile 21
    READS_DONE_BARRIER();
    STAGE_B(23, 1);
    WRITE_A(1, rA0);                                   // A(23)
    asm volatile("s_waitcnt vmcnt(4)" ::: "memory");   // B(22) landed
    asm volatile("s_waitcnt lgkmcnt(0)" ::: "memory");
    __builtin_amdgcn_s_barrier();

    COMPUTE(0);                                        // tile 22
    READS_DONE_BARRIER();
    asm volatile("s_waitcnt vmcnt(0)" ::: "memory");   // B(23) landed
    __builtin_amdgcn_s_barrier();

    COMPUTE(1);                                        // tile 23

#undef STAGE_B
#undef WRITE_A
#undef COMPUTE
#undef READS_DONE_BARRIER

    // ---- epilogue: +bias, relu, bf16 store. C layout: col=lane&15, row=(lane>>4)*4+reg
    float bv[4]; int bcol[4];
    #pragma unroll
    for (int n = 0; n < 4; ++n) { bcol[n] = wv * 64 + n * 16 + cl; bv[n] = bias1[bcol[n]]; }
    #pragma unroll
    for (int m = 0; m < 4; ++m) {
        int rbase = m0 + m * 16 + kh * 4;
        #pragma unroll
        for (int rr = 0; rr < 4; ++rr) {
            int row = rbase + rr;
            if (row < N_NODES) {
                #pragma unroll
                for (int n = 0; n < 4; ++n) {
                    float v = acc[m][n][rr] + bv[n];
                    H[(size_t)row * D1 + bcol[n]] = f2bf(fmaxf(v, 0.f));
                }
            }
        }
    }
}

// ---- GEMM2: out[16384][97] = concat(H[head], H[tail]) @ Wp + bp ----
__global__ __launch_bounds__(256) void k_gemm2(const uint16_t* __restrict__ H,
        const uint16_t* __restrict__ Wpt, const float* __restrict__ bp,
        const int* __restrict__ head, const int* __restrict__ tail,
        float* __restrict__ out) {
    __shared__ uint16_t lds_w[NOUT_PAD][40];
    const int t = threadIdx.x;
    const int lane = t & 63, wave = t >> 6;
    const int cl = lane & 15, kh = lane >> 4;
    const int rowbase = blockIdx.x * 64 + wave * 16;
    const int i_l = rowbase + cl;
    const int nodeH = head[i_l], nodeT = tail[i_l];
    const uint16_t* hH = H + (size_t)nodeH * D1 + kh * 8;
    const uint16_t* hT = H + (size_t)nodeT * D1 + kh * 8;

    f32x4 acc[7];
    const f32x4 z = {0.f, 0.f, 0.f, 0.f};
    #pragma unroll
    for (int n = 0; n < 7; ++n) acc[n] = z;

    const int wrow = t >> 1, whalf = t & 1;
    const uint16_t* wsrc = Wpt + (size_t)wrow * 1024 + whalf * 16;
    uint16_t* wdst = &lds_w[wrow][whalf * 16];

    for (int kb = 0; kb < 32; ++kb) {
        uint4 w0 = {0,0,0,0}, w1 = {0,0,0,0};
        if (t < 224) {
            const uint4* wp4 = (const uint4*)(wsrc + kb * 32);
            w0 = wp4[0]; w1 = wp4[1];
        }
        bf16x8 af = (kb < 16) ? *(const bf16x8*)(hH + kb * 32)
                              : *(const bf16x8*)(hT + (kb - 16) * 32);
        __syncthreads();
        if (t < 224) { ((uint4*)wdst)[0] = w0; ((uint4*)wdst)[1] = w1; }
        __syncthreads();
        #pragma unroll
        for (int n = 0; n < 7; ++n) {
            bf16x8 bfr = *(const bf16x8*)&lds_w[n * 16 + cl][kh * 8];
            acc[n] = __builtin_amdgcn_mfma_f32_16x16x32_bf16(af, bfr, acc[n], 0, 0, 0);
        }
    }
    #pragma unroll
    for (int n = 0; n < 7; ++n) {
        int col = n * 16 + cl;
        if (col < NOUT) {
            float bb = bp[col];
            #pragma unroll
            for (int rr = 0; rr < 4; ++rr) {
                int i = rowbase + kh * 4 + rr;
                out[(size_t)i * NOUT + col] = acc[n][rr] + bb;
            }
        }
    }
}

extern "C" void kernel_launch(void* const* d_in, const int* in_sizes, int n_in,
                              void* d_out, int out_size, void* d_ws, size_t ws_size,
                              hipStream_t stream) {
    const float* node_features = (const float*)d_in[0];
    // d_in[1] = edge_features (unused: message passing is an exact identity)
    const float* W1   = (const float*)d_in[2];
    const float* b1   = (const float*)d_in[3];
    const float* Wp   = (const float*)d_in[4];
    const float* bp   = (const float*)d_in[5];
    // d_in[6] = src (unused), d_in[7] = dst (unused)
    const int* head   = (const int*)d_in[8];
    const int* tail   = (const int*)d_in[9];
    float* out = (float*)d_out;

    char* ws = (char*)d_ws;
    uint16_t* H   = (uint16_t*)ws;
    uint16_t* W1t = (uint16_t*)(ws + (size_t)N_NODES * D1 * 2);
    uint16_t* Wpt = (uint16_t*)(ws + (size_t)N_NODES * D1 * 2 + (size_t)D1 * K1 * 2);

    const int convN = D1 * K1 + NOUT_PAD * 1024;
    k_convert<<<(convN + 255) / 256, 256, 0, stream>>>(W1, Wp, W1t, Wpt);

    k_gemm1<<<MT, 512, 0, stream>>>(node_features, W1t, b1, H);

    k_gemm2<<<NPAIR / 64, 256, 0, stream>>>(H, Wpt, bp, head, tail, out);
}